// Round 14
// baseline (170.920 us; speedup 1.0000x reference)
//
#include <hip/hip_runtime.h>
#include <hip/hip_bf16.h>

typedef short short8 __attribute__((ext_vector_type(8)));
typedef short short4v __attribute__((ext_vector_type(4)));
typedef float f32x4 __attribute__((ext_vector_type(4)));
typedef __bf16 bf16x8 __attribute__((ext_vector_type(8)));

// ---- stage a ROWSx64 bf16 tile via global_load_lds, 16B-chunk XOR swizzle --
template <int ROWS>
__device__ __forceinline__ void stage2(const __hip_bfloat16* __restrict__ g,
                                       int ld, short* lds, int t) {
    const int w = t >> 6;
    const int lane = t & 63;
#pragma unroll
    for (int i = 0; i < ROWS / 64; ++i) {
        const int cb = i * 512 + w * 64;     // wave-uniform chunk base
        const int c = cb + lane;
        const int row = c >> 3;
        const int kc = (c & 7) ^ (row & 7);
        __builtin_amdgcn_global_load_lds((const void*)(g + (long)row * ld + kc * 8),
                                         (void*)(lds + cb * 8), 16, 0, 0);
    }
}

// -------- gemm_xw v4: alpha = tanh(X_f32 * Wt^T + b) + Xt_blk co-output ----
// r12 structure. NEW: blocks with bx==0 transpose each consumed A-tile out of
// LDS (column reads, 2-way banks = free) and store Xt_blk[by][h][128 t] bf16.
// vmcnt ledger with stores in queue: writers 12/8/2, non-writers 10/6/0.
__global__ __launch_bounds__(512, 4) void gemm_xw_kernel(
    const float* __restrict__ Xf,           // [32768][1024]
    const __hip_bfloat16* __restrict__ Wt,  // [256][1024]
    __hip_bfloat16* __restrict__ alpha,     // [32768][256]
    const float* __restrict__ bias,
    __hip_bfloat16* __restrict__ XtOut) {   // [256][1024][128] bf16
    __shared__ __align__(16) short smB[3][8192];   // 16KB x3 (Wt tiles)
    __shared__ __align__(16) short smA[2][8192];   // 16KB x2 (X tiles, bf16)

    int bx = blockIdx.x, by = blockIdx.y;
    {   // T1 swizzle, nwg = 512
        const int nx = gridDim.x, ny = gridDim.y;
        const int nwg = nx * ny;
        const int lin = bx + nx * by;
        const int swz = (lin & 7) * (nwg >> 3) + (lin >> 3);
        bx = swz % nx;
        by = swz / nx;
    }
    const int byg = by;
    const bool doxt = (bx == 0);

    const int t = threadIdx.x;
    const int w = t >> 6, lane = t & 63;
    const int wm = w >> 1, wn = w & 1;   // 4 x 2 waves
    const int fr = lane & 15, quad = lane >> 4;

    const float* Ab = Xf + (long)by * 128 * 1024;
    const __hip_bfloat16* Bb = Wt + (long)bx * 128 * 1024;

    int acs[2], arow[2], akc[2];
#pragma unroll
    for (int i = 0; i < 2; ++i) {
        acs[i] = i * 512 + t;
        arow[i] = acs[i] >> 3;
        akc[i] = ((acs[i] & 7) ^ (arow[i] & 7)) * 8;
    }

    f32x4 acc[2][4] = {};
    float4 rAs[2][2][2];   // [set][granule][half] — set index always literal

#define XW_ISSUE_B(KT, BUF) stage2<128>(Bb + (KT) * 64, 1024, &smB[BUF][0], t);

#define XW_LOAD_A(KT, S)                                                        \
    _Pragma("unroll") for (int i = 0; i < 2; ++i) {                             \
        const float* src = Ab + (long)arow[i] * 1024 + (KT) * 64 + akc[i];      \
        rAs[S][i][0] = *(const float4*)(src);                                   \
        rAs[S][i][1] = *(const float4*)(src + 4);                               \
    }

#define XW_WRITE_A(BUF, S)                                                      \
    _Pragma("unroll") for (int i = 0; i < 2; ++i) {                             \
        __hip_bfloat16 tmp[8] __attribute__((aligned(16)));                     \
        tmp[0] = __float2bfloat16(rAs[S][i][0].x);                              \
        tmp[1] = __float2bfloat16(rAs[S][i][0].y);                              \
        tmp[2] = __float2bfloat16(rAs[S][i][0].z);                              \
        tmp[3] = __float2bfloat16(rAs[S][i][0].w);                              \
        tmp[4] = __float2bfloat16(rAs[S][i][1].x);                              \
        tmp[5] = __float2bfloat16(rAs[S][i][1].y);                              \
        tmp[6] = __float2bfloat16(rAs[S][i][1].z);                              \
        tmp[7] = __float2bfloat16(rAs[S][i][1].w);                              \
        *(short8*)(void*)&smA[BUF][acs[i] * 8] = *(short8*)(void*)tmp;          \
    }

// transpose co-output: column-read consumed A-tile, store Xt_blk rows.
// LDS granule (row,u) holds h-chunk (u ^ (row&7)); element (row,h) at
// row*64 + ((h>>3)^(row&7))*8 + (h&7). Banks: 2-way (free).
#define XW_XT(K)                                                                \
    if (doxt) {                                                                 \
        const short* Att = &smA[(K) % 2][0];                                    \
        const int hl = t & 63;                                                  \
        _Pragma("unroll") for (int p = 0; p < 2; ++p) {                         \
            const int trun = (t >> 6) * 2 + p;                                  \
            __hip_bfloat16 tmp2[8] __attribute__((aligned(16)));                \
            _Pragma("unroll") for (int j = 0; j < 8; ++j) {                     \
                const int row = trun * 8 + j;                                   \
                const int u = (hl >> 3) ^ (row & 7);                            \
                tmp2[j] = ((const __hip_bfloat16*)(const void*)Att)             \
                              [row * 64 + u * 8 + (hl & 7)];                    \
            }                                                                   \
            *(short8*)(void*)(XtOut +                                           \
                (((long)byg * 1024) + (K) * 64 + hl) * 128 + trun * 8) =        \
                *(short8*)(void*)tmp2;                                          \
        }                                                                       \
    }

    // prologue: A(0)->E->LDS0, B(0),B(1) glds, A(1)->O, A(2)->E
    XW_LOAD_A(0, 0)
    XW_ISSUE_B(0, 0)
    XW_ISSUE_B(1, 1)
    XW_WRITE_A(0, 0)
    XW_LOAD_A(1, 1)
    XW_LOAD_A(2, 0)
    __builtin_amdgcn_sched_barrier(0);
    asm volatile("s_waitcnt vmcnt(10)" ::: "memory");
    asm volatile("s_waitcnt lgkmcnt(0)" ::: "memory");
    __builtin_amdgcn_s_barrier();
    __builtin_amdgcn_sched_barrier(0);

#define XW_STEP(K)                                                              \
    {                                                                           \
        if ((K) + 2 < 16) { XW_ISSUE_B((K) + 2, ((K) + 2) % 3) }                \
        const short* At_ = &smA[(K) % 2][0];                                    \
        const short* Bt_ = &smB[(K) % 3][0];                                    \
        _Pragma("unroll") for (int ks = 0; ks < 2; ++ks) {                      \
            bf16x8 af[2], bfv[4];                                               \
            const int kc = ks * 4 + quad;                                       \
            _Pragma("unroll") for (int m = 0; m < 2; ++m) {                     \
                const int row = wm * 32 + m * 16 + fr;                          \
                const int chunk = row * 8 + (kc ^ (row & 7));                   \
                af[m] = *(const bf16x8*)(const void*)(At_ + chunk * 8);         \
            }                                                                   \
            _Pragma("unroll") for (int n = 0; n < 4; ++n) {                     \
                const int row = wn * 64 + n * 16 + fr;                          \
                const int chunk = row * 8 + (kc ^ (row & 7));                   \
                bfv[n] = *(const bf16x8*)(const void*)(Bt_ + chunk * 8);        \
            }                                                                   \
            _Pragma("unroll") for (int m = 0; m < 2; ++m)                       \
                _Pragma("unroll") for (int n = 0; n < 4; ++n)                   \
                    acc[m][n] = __builtin_amdgcn_mfma_f32_16x16x32_bf16(        \
                        af[m], bfv[n], acc[m][n], 0, 0, 0);                     \
        }                                                                       \
        XW_XT(K)                                                                \
        if ((K) + 1 < 16) { XW_WRITE_A(((K) + 1) % 2, ((K) + 1) & 1) }          \
        if ((K) + 3 < 16) { XW_LOAD_A((K) + 3, ((K) + 1) & 1) }                 \
        __builtin_amdgcn_sched_barrier(0);                                      \
        if ((K) + 3 < 16) {                                                     \
            if (doxt) asm volatile("s_waitcnt vmcnt(12)" ::: "memory");         \
            else      asm volatile("s_waitcnt vmcnt(10)" ::: "memory");         \
        } else if ((K) + 2 < 16) {                                              \
            if (doxt) asm volatile("s_waitcnt vmcnt(8)" ::: "memory");          \
            else      asm volatile("s_waitcnt vmcnt(6)" ::: "memory");          \
        } else if ((K) + 1 < 16) {                                              \
            if (doxt) asm volatile("s_waitcnt vmcnt(2)" ::: "memory");          \
            else      asm volatile("s_waitcnt vmcnt(0)" ::: "memory");          \
        }                                                                       \
        if ((K) + 1 < 16) {                                                     \
            asm volatile("s_waitcnt lgkmcnt(0)" ::: "memory");                  \
            __builtin_amdgcn_s_barrier();                                       \
            __builtin_amdgcn_sched_barrier(0);                                  \
        }                                                                       \
    }

    XW_STEP(0)  XW_STEP(1)  XW_STEP(2)  XW_STEP(3)
    XW_STEP(4)  XW_STEP(5)  XW_STEP(6)  XW_STEP(7)
    XW_STEP(8)  XW_STEP(9)  XW_STEP(10) XW_STEP(11)
    XW_STEP(12) XW_STEP(13) XW_STEP(14) XW_STEP(15)
#undef XW_STEP
#undef XW_XT
#undef XW_ISSUE_B
#undef XW_LOAD_A
#undef XW_WRITE_A

    const long rowBase = (long)by * 128 + wm * 32;
    const int colBase = bx * 128 + wn * 64;
#pragma unroll
    for (int m = 0; m < 2; ++m) {
#pragma unroll
        for (int n = 0; n < 4; ++n) {
            const int col = colBase + n * 16 + fr;
            const float bv = bias[col];
#pragma unroll
            for (int j = 0; j < 4; ++j) {
                const long row = rowBase + m * 16 + quad * 4 + j;
                alpha[row * 256 + col] = __float2bfloat16(tanhf(acc[m][n][j] + bv));
            }
        }
    }
}

// -------- gemm_pv v7: occupancy-first streaming on bf16 Xt_blk -------------
// Tile 128t x 128h x BK=32s, K=512 -> 16 steps. 512 thr = 8 waves (4x2),
// wave tile 32x64, acc 2x4 = 32 VGPR. Both operands glds with the r9-verified
// 4-chunk XOR pair. LDS 2x(8+8) = 32KB -> ~3 blocks/CU (~24 waves). Simple
// single-barrier dbuf; TLP hides latency. Grid (8,4,64) = 2048 blocks.
__global__ __launch_bounds__(512, 4) void gemm_pv_kernel(
    const __hip_bfloat16* __restrict__ P,   // [B*512][512]
    const __hip_bfloat16* __restrict__ Xt,  // [256][1024][128] bf16 blocked
    float* __restrict__ Z) {                // [B*512][1024]
    __shared__ __align__(16) short smA[2][4096];   // 8KB: P tile [128t][32s]
    __shared__ __align__(16) short smB[2][4096];   // 8KB: Xt tile [128h][32s]

    int bx = blockIdx.x, by = blockIdx.y, bz = blockIdx.z;
    {   // T1 bijective XCD-chunked swizzle, nwg = 8*4*64 = 2048
        const int nx = gridDim.x, ny = gridDim.y;
        const int nwg = nx * ny * gridDim.z;
        const int lin = bx + nx * (by + ny * bz);
        const int swz = (lin & 7) * (nwg >> 3) + (lin >> 3);
        bx = swz % nx;
        const int r = swz / nx;
        by = r % ny;
        bz = r / ny;
    }

    const int t = threadIdx.x;
    const int w = t >> 6, lane = t & 63;
    const int wm = w >> 1, wn = w & 1;   // 4 x 2 waves
    const int fr = lane & 15, quad = lane >> 4;

    const __hip_bfloat16* Ab = P + ((long)bz * 512 + by * 128) * 512;

    // granule c = t (one per thread per operand): row = c>>2,
    // source chunk = (c&3) ^ ((row>>1)&3)  [r9-verified write/read pair]
    const int grow = t >> 2;
    const int gkc = ((t & 3) ^ ((grow >> 1) & 3)) * 8;

#define PV_STAGE(KT, BUF)                                                       \
    {                                                                           \
        __builtin_amdgcn_global_load_lds(                                       \
            (const void*)(Ab + (long)grow * 512 + (KT) * 32 + gkc),             \
            (void*)(&smA[BUF][t * 8]), 16, 0, 0);                               \
        const __hip_bfloat16* bsrc = Xt +                                       \
            ((long)(bz * 4 + ((KT) >> 2)) * 1024 + bx * 128 + grow) * 128 +     \
            ((KT) & 3) * 32 + gkc;                                              \
        __builtin_amdgcn_global_load_lds((const void*)bsrc,                     \
                                         (void*)(&smB[BUF][t * 8]), 16, 0, 0);  \
    }

    f32x4 acc[2][4] = {};

    PV_STAGE(0, 0)
    __syncthreads();

    int cur = 0;
    for (int kt = 0; kt < 16; ++kt) {
        if (kt + 1 < 16) PV_STAGE(kt + 1, cur ^ 1)
        const short* At_ = &smA[cur][0];
        const short* Bt_ = &smB[cur][0];
        bf16x8 bfv[4];
#pragma unroll
        for (int n = 0; n < 4; ++n) {
            const int row = wn * 64 + n * 16 + fr;
            const int slot = row * 4 + (quad ^ ((row >> 1) & 3));
            bfv[n] = *(const bf16x8*)(const void*)(Bt_ + slot * 8);
        }
#pragma unroll
        for (int m = 0; m < 2; ++m) {
            const int row = wm * 32 + m * 16 + fr;
            const int slot = row * 4 + (quad ^ ((row >> 1) & 3));
            const bf16x8 af = *(const bf16x8*)(const void*)(At_ + slot * 8);
#pragma unroll
            for (int n = 0; n < 4; ++n)
                acc[m][n] = __builtin_amdgcn_mfma_f32_16x16x32_bf16(
                    af, bfv[n], acc[m][n], 0, 0, 0);
        }
        __syncthreads();   // drains vmcnt -> next tile ready, cur reusable
        cur ^= 1;
    }
#undef PV_STAGE

    const long rowBase = (long)bz * 512 + by * 128 + wm * 32;
    const int colBase = bx * 128 + wn * 64;
#pragma unroll
    for (int m = 0; m < 2; ++m) {
#pragma unroll
        for (int n = 0; n < 4; ++n) {
            const int col = colBase + n * 16 + fr;
#pragma unroll
            for (int j = 0; j < 4; ++j) {
                const long row = rowBase + m * 16 + quad * 4 + j;
                Z[row * 1024 + col] = acc[m][n][j];
            }
        }
    }
}

// naive small transpose+convert: in [R][C] f32 -> out [C][R] bf16
__global__ __launch_bounds__(256) void transpose_cvt_kernel(const float* __restrict__ in,
                                                            __hip_bfloat16* __restrict__ out,
                                                            int R, int C) {
    const int o = blockIdx.x * 256 + threadIdx.x;
    if (o >= R * C) return;
    const int c = o / R;
    const int r = o - c * R;
    out[o] = __float2bfloat16(in[(long)r * C + c]);
}

// -------- score_softmax v2: barrier-free K-loop (unchanged from r12) -------
__global__ __launch_bounds__(512, 4) void score_softmax_kernel(
    const __hip_bfloat16* __restrict__ Aa,  // alpha [32768][256]
    const __hip_bfloat16* __restrict__ Ut,  // [512][256]
    __hip_bfloat16* __restrict__ P,         // [32768][512]
    const int* __restrict__ sen) {
    __shared__ __align__(16) short At[2048 * 8];   // 32KB
    __shared__ float red[2][64][9];

    const int t = threadIdx.x;
    const int w = t >> 6, lane = t & 63;
    const int fr = lane & 15, quad = lane >> 4;
    const long row0 = (long)blockIdx.x * 64;
    const __hip_bfloat16* Ab = Aa + row0 * 256;

#pragma unroll
    for (int i = 0; i < 4; ++i) {
        const int cb = i * 512 + w * 64;
        const int c = cb + lane;
        const int row = c >> 5;
        const int kc = (c & 31) ^ (row & 7);
        __builtin_amdgcn_global_load_lds(
            (const void*)(Ab + (long)row * 256 + kc * 8),
            (void*)(At + cb * 8), 16, 0, 0);
    }

    f32x4 acc[4][4] = {};
    bf16x8 bfvs[2][4];

#define SM_LOAD_B(KT, S)                                                        \
    _Pragma("unroll") for (int n = 0; n < 4; ++n)                               \
        bfvs[S][n] = *(const bf16x8*)(const void*)(                             \
            Ut + (w * 64 + n * 16 + fr) * 256 + (KT) * 32 + quad * 8);

    SM_LOAD_B(0, 0)
    SM_LOAD_B(1, 1)
    __builtin_amdgcn_sched_barrier(0);
    asm volatile("s_waitcnt vmcnt(8)" ::: "memory");
    __builtin_amdgcn_s_barrier();
    __builtin_amdgcn_sched_barrier(0);

#define SM_STEP(KT)                                                             \
    {                                                                           \
        bf16x8 af[4];                                                           \
        _Pragma("unroll") for (int m = 0; m < 4; ++m) {                         \
            const int row = m * 16 + fr;                                        \
            const int g = row * 32 + (((KT) * 4 + quad) ^ (row & 7));           \
            af[m] = *(const bf16x8*)(const void*)(At + g * 8);                  \
        }                                                                       \
        _Pragma("unroll") for (int m = 0; m < 4; ++m)                           \
            _Pragma("unroll") for (int n = 0; n < 4; ++n)                       \
                acc[m][n] = __builtin_amdgcn_mfma_f32_16x16x32_bf16(            \
                    af[m], bfvs[(KT) & 1][n], acc[m][n], 0, 0, 0);              \
        if ((KT) + 2 < 8) { SM_LOAD_B((KT) + 2, (KT) & 1) }                     \
    }

    SM_STEP(0) SM_STEP(1) SM_STEP(2) SM_STEP(3)
    SM_STEP(4) SM_STEP(5) SM_STEP(6) SM_STEP(7)
#undef SM_STEP
#undef SM_LOAD_B
    __syncthreads();

    const int L = sen[row0 >> 9];
    bool valid[4];
#pragma unroll
    for (int n = 0; n < 4; ++n) valid[n] = (w * 64 + n * 16 + fr) < L;

    float mx[4][4];
#pragma unroll
    for (int m = 0; m < 4; ++m)
#pragma unroll
        for (int j = 0; j < 4; ++j) {
            float v = -3.0e38f;
#pragma unroll
            for (int n = 0; n < 4; ++n)
                if (valid[n]) v = fmaxf(v, acc[m][n][j]);
#pragma unroll
            for (int off = 8; off >= 1; off >>= 1) v = fmaxf(v, __shfl_xor(v, off, 64));
            mx[m][j] = v;
        }
    if (fr == 0) {
#pragma unroll
        for (int m = 0; m < 4; ++m)
#pragma unroll
            for (int j = 0; j < 4; ++j) red[0][m * 16 + quad * 4 + j][w] = mx[m][j];
    }
    __syncthreads();
    float rmax[4][4];
#pragma unroll
    for (int m = 0; m < 4; ++m)
#pragma unroll
        for (int j = 0; j < 4; ++j) {
            const int row = m * 16 + quad * 4 + j;
            float v = red[0][row][0];
#pragma unroll
            for (int ww = 1; ww < 8; ++ww) v = fmaxf(v, red[0][row][ww]);
            rmax[m][j] = v;
        }

    float sum[4][4];
#pragma unroll
    for (int m = 0; m < 4; ++m)
#pragma unroll
        for (int j = 0; j < 4; ++j) {
            float s = 0.f;
#pragma unroll
            for (int n = 0; n < 4; ++n) {
                float e = valid[n] ? __expf(acc[m][n][j] - rmax[m][j]) : 0.f;
                acc[m][n][j] = e;
                s += e;
            }
#pragma unroll
            for (int off = 8; off >= 1; off >>= 1) s += __shfl_xor(s, off, 64);
            sum[m][j] = s;
        }
    if (fr == 0) {
#pragma unroll
        for (int m = 0; m < 4; ++m)
#pragma unroll
            for (int j = 0; j < 4; ++j) red[1][m * 16 + quad * 4 + j][w] = sum[m][j];
    }
    __syncthreads();
#pragma unroll
    for (int m = 0; m < 4; ++m)
#pragma unroll
        for (int j = 0; j < 4; ++j) {
            const int row = m * 16 + quad * 4 + j;
            float s = 0.f;
#pragma unroll
            for (int ww = 0; ww < 8; ++ww) s += red[1][row][ww];
            const float inv = 1.f / s;
#pragma unroll
            for (int n = 0; n < 4; ++n)
                P[(row0 + row) * 512 + w * 64 + n * 16 + fr] =
                    __float2bfloat16(acc[m][n][j] * inv);
        }
}

extern "C" void kernel_launch(void* const* d_in, const int* in_sizes, int n_in,
                              void* d_out, int out_size, void* d_ws, size_t ws_size,
                              hipStream_t stream) {
    const float* X = (const float*)d_in[0];
    const int* sen = (const int*)d_in[1];
    const float* W = (const float*)d_in[2];
    const float* bias = (const float*)d_in[3];
    const float* U = (const float*)d_in[4];
    float* out = (float*)d_out;

    const int B = 64, T = 512, H = 1024, A = 256;
    const long M = (long)B * T;  // 32768

    // workspace: P (32Mi) | Xt_blk (64Mi) | Wt (0.5Mi) | Ut (0.25Mi)
    char* ws = (char*)d_ws;
    __hip_bfloat16* Pbf = (__hip_bfloat16*)ws;
    __hip_bfloat16* Xtb = (__hip_bfloat16*)(ws + M * T * 2);
    __hip_bfloat16* Wt = (__hip_bfloat16*)(ws + M * T * 2 + M * H * 2);
    __hip_bfloat16* Ut = (__hip_bfloat16*)((char*)Wt + (long)H * A * 2);

    // d_out scratch: alpha bf16 at [64Mi,80Mi) — consumed by score_softmax
    // before gemm_pv overwrites all of d_out with Z.
    __hip_bfloat16* alpha = (__hip_bfloat16*)((char*)d_out + M * H * 2);

    // 1. W^T [A][H], U^T [T][A]
    transpose_cvt_kernel<<<(H * A) / 256, 256, 0, stream>>>(W, Wt, H, A);
    transpose_cvt_kernel<<<(A * T) / 256, 256, 0, stream>>>(U, Ut, A, T);
    // 2. alpha = tanh(X*W + b) + Xt_blk bf16 co-output
    gemm_xw_kernel<<<dim3(2, 256), 512, 0, stream>>>(X, Wt, alpha, bias, Xtb);
    // 3. P = softmax(alpha * U^T, mask) — barrier-free K-loop
    score_softmax_kernel<<<(int)(M / 64), 512, 0, stream>>>(alpha, Ut, Pbf, sen);
    // 4. Z = P * X — v7: bf16 Xt_blk, 32KB LDS, high occupancy streaming
    gemm_pv_kernel<<<dim3(8, 4, B), 512, 0, stream>>>(Pbf, Xtb, out);
}

// Round 15
// 148.790 us; speedup vs baseline: 1.1487x; 1.1487x over previous
//
#include <hip/hip_runtime.h>
#include <hip/hip_bf16.h>

typedef short short8 __attribute__((ext_vector_type(8)));
typedef short short4v __attribute__((ext_vector_type(4)));
typedef float f32x4 __attribute__((ext_vector_type(4)));
typedef __bf16 bf16x8 __attribute__((ext_vector_type(8)));

// ---- stage a ROWSx64 bf16 tile via global_load_lds, 16B-chunk XOR swizzle --
template <int ROWS>
__device__ __forceinline__ void stage2(const __hip_bfloat16* __restrict__ g,
                                       int ld, short* lds, int t) {
    const int w = t >> 6;
    const int lane = t & 63;
#pragma unroll
    for (int i = 0; i < ROWS / 64; ++i) {
        const int cb = i * 512 + w * 64;     // wave-uniform chunk base
        const int c = cb + lane;
        const int row = c >> 3;
        const int kc = (c & 7) ^ (row & 7);
        __builtin_amdgcn_global_load_lds((const void*)(g + (long)row * ld + kc * 8),
                                         (void*)(lds + cb * 8), 16, 0, 0);
    }
}

// -------- gemm_xw (r11 v2, measured-best ~43 us): alpha = tanh(X*Wt^T + b) --
// BM=128(t) x BN=128(a) x BK=64(h), K=1024 -> 16 steps. Grid (2,256)=512 wgs.
// 8 waves (4x2), wave tile 32x64. B: glds triple-buffered; A: reg-staged
// (depth-1), cvt->ds_write, double-buffered. Counted vmcnt(6).
__global__ __launch_bounds__(512, 4) void gemm_xw_kernel(
    const float* __restrict__ Xf,           // [32768][1024]
    const __hip_bfloat16* __restrict__ Wt,  // [256][1024]
    __hip_bfloat16* __restrict__ alpha,     // [32768][256]
    const float* __restrict__ bias) {
    __shared__ __align__(16) short smB[3][8192];   // 16KB x3 (Wt tiles)
    __shared__ __align__(16) short smA[2][8192];   // 16KB x2 (X tiles, bf16)

    int bx = blockIdx.x, by = blockIdx.y;
    {   // T1 swizzle, nwg = 512
        const int nx = gridDim.x, ny = gridDim.y;
        const int nwg = nx * ny;
        const int lin = bx + nx * by;
        const int swz = (lin & 7) * (nwg >> 3) + (lin >> 3);
        bx = swz % nx;
        by = swz / nx;
    }

    const int t = threadIdx.x;
    const int w = t >> 6, lane = t & 63;
    const int wm = w >> 1, wn = w & 1;   // 4 x 2 waves
    const int fr = lane & 15, quad = lane >> 4;

    const float* Ab = Xf + (long)by * 128 * 1024;
    const __hip_bfloat16* Bb = Wt + (long)bx * 128 * 1024;

    int acs[2], arow[2], akc[2];
#pragma unroll
    for (int i = 0; i < 2; ++i) {
        acs[i] = i * 512 + t;
        arow[i] = acs[i] >> 3;
        akc[i] = ((acs[i] & 7) ^ (arow[i] & 7)) * 8;
    }

    f32x4 acc[2][4] = {};
    float4 rA[2][2];

#define XW_ISSUE_B(KT, BUF) stage2<128>(Bb + (KT) * 64, 1024, &smB[BUF][0], t);

#define XW_LOAD_A(KT)                                                           \
    _Pragma("unroll") for (int i = 0; i < 2; ++i) {                             \
        const float* src = Ab + (long)arow[i] * 1024 + (KT) * 64 + akc[i];      \
        rA[i][0] = *(const float4*)(src);                                       \
        rA[i][1] = *(const float4*)(src + 4);                                   \
    }

#define XW_WRITE_A(BUF)                                                         \
    _Pragma("unroll") for (int i = 0; i < 2; ++i) {                             \
        __hip_bfloat16 tmp[8] __attribute__((aligned(16)));                     \
        tmp[0] = __float2bfloat16(rA[i][0].x);                                  \
        tmp[1] = __float2bfloat16(rA[i][0].y);                                  \
        tmp[2] = __float2bfloat16(rA[i][0].z);                                  \
        tmp[3] = __float2bfloat16(rA[i][0].w);                                  \
        tmp[4] = __float2bfloat16(rA[i][1].x);                                  \
        tmp[5] = __float2bfloat16(rA[i][1].y);                                  \
        tmp[6] = __float2bfloat16(rA[i][1].z);                                  \
        tmp[7] = __float2bfloat16(rA[i][1].w);                                  \
        *(short8*)(void*)&smA[BUF][acs[i] * 8] = *(short8*)(void*)tmp;          \
    }

    XW_ISSUE_B(0, 0)
    XW_ISSUE_B(1, 1)
    XW_LOAD_A(0)
    XW_WRITE_A(0)          // auto-waits on A(0) regs
    XW_LOAD_A(1)
    __builtin_amdgcn_sched_barrier(0);
    asm volatile("s_waitcnt vmcnt(4)" ::: "memory");
    asm volatile("s_waitcnt lgkmcnt(0)" ::: "memory");
    __builtin_amdgcn_s_barrier();
    __builtin_amdgcn_sched_barrier(0);

#pragma unroll
    for (int k = 0; k < 16; ++k) {
        if (k + 2 < 16) XW_ISSUE_B(k + 2, (k + 2) % 3)
        {
            const short* At = &smA[k % 2][0];
            const short* Bt = &smB[k % 3][0];
#pragma unroll
            for (int ks = 0; ks < 2; ++ks) {
                bf16x8 af[2], bfv[4];
                const int kc = ks * 4 + quad;
#pragma unroll
                for (int m = 0; m < 2; ++m) {
                    const int row = wm * 32 + m * 16 + fr;
                    const int chunk = row * 8 + (kc ^ (row & 7));
                    af[m] = *(const bf16x8*)(const void*)(At + chunk * 8);
                }
#pragma unroll
                for (int n = 0; n < 4; ++n) {
                    const int row = wn * 64 + n * 16 + fr;
                    const int chunk = row * 8 + (kc ^ (row & 7));
                    bfv[n] = *(const bf16x8*)(const void*)(Bt + chunk * 8);
                }
#pragma unroll
                for (int m = 0; m < 2; ++m)
#pragma unroll
                    for (int n = 0; n < 4; ++n)
                        acc[m][n] = __builtin_amdgcn_mfma_f32_16x16x32_bf16(
                            af[m], bfv[n], acc[m][n], 0, 0, 0);
            }
        }
        if (k + 1 < 16) XW_WRITE_A((k + 1) % 2)   // auto-waits on A(k+1) regs
        if (k + 2 < 16) XW_LOAD_A(k + 2)
        __builtin_amdgcn_sched_barrier(0);
        if (k + 2 < 16) {
            asm volatile("s_waitcnt vmcnt(6)" ::: "memory");
        } else if (k + 1 < 16) {
            asm volatile("s_waitcnt vmcnt(0)" ::: "memory");
        }
        if (k + 1 < 16) {
            asm volatile("s_waitcnt lgkmcnt(0)" ::: "memory");
            __builtin_amdgcn_s_barrier();
            __builtin_amdgcn_sched_barrier(0);
        }
    }
#undef XW_ISSUE_B
#undef XW_LOAD_A
#undef XW_WRITE_A

    const long rowBase = (long)by * 128 + wm * 32;
    const int colBase = bx * 128 + wn * 64;
#pragma unroll
    for (int m = 0; m < 2; ++m) {
#pragma unroll
        for (int n = 0; n < 4; ++n) {
            const int col = colBase + n * 16 + fr;
            const float bv = bias[col];
#pragma unroll
            for (int j = 0; j < 4; ++j) {
                const long row = rowBase + m * 16 + quad * 4 + j;
                alpha[row * 256 + col] = __float2bfloat16(tanhf(acc[m][n][j] + bv));
            }
        }
    }
}

// -------- gemm_pv v9: v5 structure + chunk-XOR swizzle (conflict A/B) ------
// Tile 256t x 128h x BK=32s. A (P bf16): glds slot-XOR (r9-verified), 3-buf.
// B (X f32): glds LINEAR dest, SOURCE chunk-XOR csrc = c ^ ((s>>3)<<1) so the
// column reads hit <=2-way banks (free, m136) instead of v5's 4-way.
// Read: phys chunk = (h>>2) ^ (quad<<1)  [s>>3 == quad for s = quad*8+j].
// Counted vmcnt(4): tile k+1 forced, k+2 in flight. 96KB -> 1 block/CU.
__global__ __launch_bounds__(512, 2) void gemm_pv_kernel(
    const __hip_bfloat16* __restrict__ P,  // [B*512][512]
    const float* __restrict__ Xf,          // [B*512][1024]
    float* __restrict__ Z) {               // [B*512][1024]
    __shared__ __align__(16) short smA[3][8192];   // 16KB x3 (P bf16)
    __shared__ __align__(16) float smB[3][4096];   // 16KB x3 (X f32)

    int bx = blockIdx.x, by = blockIdx.y, bz = blockIdx.z;
    {   // T1 bijective XCD-chunked swizzle, nwg = 8*2*64 = 1024
        const int nx = gridDim.x, ny = gridDim.y;
        const int nwg = nx * ny * gridDim.z;
        const int lin = bx + nx * (by + ny * bz);
        const int swz = (lin & 7) * (nwg >> 3) + (lin >> 3);
        bx = swz % nx;
        const int r = swz / nx;
        by = r % ny;
        bz = r / ny;
    }

    const int t = threadIdx.x;
    const int w = t >> 6, lane = t & 63;
    const int wm = w >> 1, wn = w & 1;   // 4 x 2 waves
    const int fr = lane & 15, quad = lane >> 4;

    const __hip_bfloat16* Ab = P + ((long)bz * 512 + by * 256) * 512;
    const float* Bb = Xf + (long)bz * 512 * 1024 + bx * 128;

    // A staging slots (2 granules per thread) — r9-verified mapping
    int acb[2], arow[2], akc[2];
#pragma unroll
    for (int i = 0; i < 2; ++i) {
        acb[i] = i * 512 + w * 64;           // wave-uniform
        const int s = acb[i] + lane;
        arow[i] = s >> 2;
        akc[i] = ((s & 3) ^ ((arow[i] >> 1) & 3)) * 8;
    }

    f32x4 acc[4][4] = {};

#define PV_ISSUE_A(KT, BUF)                                                     \
    _Pragma("unroll") for (int i = 0; i < 2; ++i)                               \
        __builtin_amdgcn_global_load_lds(                                       \
            (const void*)(Ab + (long)arow[i] * 512 + (KT) * 32 + akc[i]),       \
            (void*)(&smA[BUF][acb[i] * 8]), 16, 0, 0);

// B: granule g: s = g>>5 (tile row), phys chunk = g&31, SOURCE chunk
// csrc = (g&31) ^ ((s>>3)<<1). Per-row 512B stays one coalesced segment
// (chunks permuted within the row). LDS dest linear.
#define PV_ISSUE_B(KT, BUF)                                                     \
    _Pragma("unroll") for (int i = 0; i < 2; ++i) {                             \
        const int g = i * 512 + t;                                              \
        const int s_ = g >> 5;                                                  \
        const int csrc = (g & 31) ^ ((s_ >> 3) << 1);                           \
        __builtin_amdgcn_global_load_lds(                                       \
            (const void*)(Bb + (long)((KT) * 32 + s_) * 1024 + csrc * 4),       \
            (void*)(&smB[BUF][(i * 512 + w * 64) * 4]), 16, 0, 0);              \
    }

    // prologue: tile0 -> bufs 0, tile1 -> bufs 1
    PV_ISSUE_A(0, 0)
    PV_ISSUE_B(0, 0)
    PV_ISSUE_A(1, 1)
    PV_ISSUE_B(1, 1)
    __builtin_amdgcn_sched_barrier(0);
    asm volatile("s_waitcnt vmcnt(4)" ::: "memory");   // tile0 landed; tile1 flies
    __builtin_amdgcn_s_barrier();
    __builtin_amdgcn_sched_barrier(0);

#define PV_STEP(K)                                                              \
    {                                                                           \
        if ((K) + 2 < 16) {                                                     \
            PV_ISSUE_A((K) + 2, ((K) + 2) % 3)                                  \
            PV_ISSUE_B((K) + 2, ((K) + 2) % 3)                                  \
        }                                                                       \
        const short* At_ = &smA[(K) % 3][0];                                    \
        const float* Bt_ = &smB[(K) % 3][0];                                    \
        bf16x8 bfv[4];                                                          \
        _Pragma("unroll") for (int n = 0; n < 4; ++n) {                         \
            const int h = wn * 64 + n * 16 + fr;                                \
            const float* colp = Bt_ + quad * 8 * 128 +                          \
                                (((h >> 2) ^ (quad << 1)) << 2) + (h & 3);      \
            __hip_bfloat16 tmp[8] __attribute__((aligned(16)));                 \
            _Pragma("unroll") for (int j = 0; j < 8; ++j)                       \
                tmp[j] = __float2bfloat16(colp[j * 128]);                       \
            bfv[n] = *(bf16x8*)(void*)tmp;                                      \
        }                                                                       \
        _Pragma("unroll") for (int m = 0; m < 4; ++m) {                         \
            const int row = wm * 64 + m * 16 + fr;                              \
            const int slot = row * 4 + (quad ^ ((row >> 1) & 3));               \
            const bf16x8 af = *(const bf16x8*)(const void*)(At_ + slot * 8);    \
            _Pragma("unroll") for (int n = 0; n < 4; ++n)                       \
                acc[m][n] = __builtin_amdgcn_mfma_f32_16x16x32_bf16(            \
                    af, bfv[n], acc[m][n], 0, 0, 0);                            \
        }                                                                       \
        __builtin_amdgcn_sched_barrier(0);                                      \
        if ((K) + 2 < 16) {                                                     \
            asm volatile("s_waitcnt vmcnt(4)" ::: "memory");                    \
        } else if ((K) + 1 < 16) {                                              \
            asm volatile("s_waitcnt vmcnt(0)" ::: "memory");                    \
        }                                                                       \
        if ((K) + 1 < 16) {                                                     \
            __builtin_amdgcn_s_barrier();                                       \
            __builtin_amdgcn_sched_barrier(0);                                  \
        }                                                                       \
    }

    PV_STEP(0)  PV_STEP(1)  PV_STEP(2)  PV_STEP(3)
    PV_STEP(4)  PV_STEP(5)  PV_STEP(6)  PV_STEP(7)
    PV_STEP(8)  PV_STEP(9)  PV_STEP(10) PV_STEP(11)
    PV_STEP(12) PV_STEP(13) PV_STEP(14) PV_STEP(15)
#undef PV_STEP
#undef PV_ISSUE_A
#undef PV_ISSUE_B

    const long rowBase = (long)bz * 512 + by * 256 + wm * 64;
    const int colBase = bx * 128 + wn * 64;
#pragma unroll
    for (int m = 0; m < 4; ++m) {
#pragma unroll
        for (int n = 0; n < 4; ++n) {
            const int col = colBase + n * 16 + fr;
#pragma unroll
            for (int j = 0; j < 4; ++j) {
                const long row = rowBase + m * 16 + quad * 4 + j;
                Z[row * 1024 + col] = acc[m][n][j];
            }
        }
    }
}

// naive small transpose+convert: in [R][C] f32 -> out [C][R] bf16
__global__ __launch_bounds__(256) void transpose_cvt_kernel(const float* __restrict__ in,
                                                            __hip_bfloat16* __restrict__ out,
                                                            int R, int C) {
    const int o = blockIdx.x * 256 + threadIdx.x;
    if (o >= R * C) return;
    const int c = o / R;
    const int r = o - c * R;
    out[o] = __float2bfloat16(in[(long)r * C + c]);
}

// -------- score_softmax v2: barrier-free K-loop (r12, unchanged) -----------
__global__ __launch_bounds__(512, 4) void score_softmax_kernel(
    const __hip_bfloat16* __restrict__ Aa,  // alpha [32768][256]
    const __hip_bfloat16* __restrict__ Ut,  // [512][256]
    __hip_bfloat16* __restrict__ P,         // [32768][512]
    const int* __restrict__ sen) {
    __shared__ __align__(16) short At[2048 * 8];   // 32KB
    __shared__ float red[2][64][9];

    const int t = threadIdx.x;
    const int w = t >> 6, lane = t & 63;
    const int fr = lane & 15, quad = lane >> 4;
    const long row0 = (long)blockIdx.x * 64;
    const __hip_bfloat16* Ab = Aa + row0 * 256;

#pragma unroll
    for (int i = 0; i < 4; ++i) {
        const int cb = i * 512 + w * 64;
        const int c = cb + lane;
        const int row = c >> 5;
        const int kc = (c & 31) ^ (row & 7);
        __builtin_amdgcn_global_load_lds(
            (const void*)(Ab + (long)row * 256 + kc * 8),
            (void*)(At + cb * 8), 16, 0, 0);
    }

    f32x4 acc[4][4] = {};
    bf16x8 bfvs[2][4];

#define SM_LOAD_B(KT, S)                                                        \
    _Pragma("unroll") for (int n = 0; n < 4; ++n)                               \
        bfvs[S][n] = *(const bf16x8*)(const void*)(                             \
            Ut + (w * 64 + n * 16 + fr) * 256 + (KT) * 32 + quad * 8);

    SM_LOAD_B(0, 0)
    SM_LOAD_B(1, 1)
    __builtin_amdgcn_sched_barrier(0);
    asm volatile("s_waitcnt vmcnt(8)" ::: "memory");
    __builtin_amdgcn_s_barrier();
    __builtin_amdgcn_sched_barrier(0);

#define SM_STEP(KT)                                                             \
    {                                                                           \
        bf16x8 af[4];                                                           \
        _Pragma("unroll") for (int m = 0; m < 4; ++m) {                         \
            const int row = m * 16 + fr;                                        \
            const int g = row * 32 + (((KT) * 4 + quad) ^ (row & 7));           \
            af[m] = *(const bf16x8*)(const void*)(At + g * 8);                  \
        }                                                                       \
        _Pragma("unroll") for (int m = 0; m < 4; ++m)                           \
            _Pragma("unroll") for (int n = 0; n < 4; ++n)                       \
                acc[m][n] = __builtin_amdgcn_mfma_f32_16x16x32_bf16(            \
                    af[m], bfvs[(KT) & 1][n], acc[m][n], 0, 0, 0);              \
        if ((KT) + 2 < 8) { SM_LOAD_B((KT) + 2, (KT) & 1) }                     \
    }

    SM_STEP(0) SM_STEP(1) SM_STEP(2) SM_STEP(3)
    SM_STEP(4) SM_STEP(5) SM_STEP(6) SM_STEP(7)
#undef SM_STEP
#undef SM_LOAD_B
    __syncthreads();

    const int L = sen[row0 >> 9];
    bool valid[4];
#pragma unroll
    for (int n = 0; n < 4; ++n) valid[n] = (w * 64 + n * 16 + fr) < L;

    float mx[4][4];
#pragma unroll
    for (int m = 0; m < 4; ++m)
#pragma unroll
        for (int j = 0; j < 4; ++j) {
            float v = -3.0e38f;
#pragma unroll
            for (int n = 0; n < 4; ++n)
                if (valid[n]) v = fmaxf(v, acc[m][n][j]);
#pragma unroll
            for (int off = 8; off >= 1; off >>= 1) v = fmaxf(v, __shfl_xor(v, off, 64));
            mx[m][j] = v;
        }
    if (fr == 0) {
#pragma unroll
        for (int m = 0; m < 4; ++m)
#pragma unroll
            for (int j = 0; j < 4; ++j) red[0][m * 16 + quad * 4 + j][w] = mx[m][j];
    }
    __syncthreads();
    float rmax[4][4];
#pragma unroll
    for (int m = 0; m < 4; ++m)
#pragma unroll
        for (int j = 0; j < 4; ++j) {
            const int row = m * 16 + quad * 4 + j;
            float v = red[0][row][0];
#pragma unroll
            for (int ww = 1; ww < 8; ++ww) v = fmaxf(v, red[0][row][ww]);
            rmax[m][j] = v;
        }

    float sum[4][4];
#pragma unroll
    for (int m = 0; m < 4; ++m)
#pragma unroll
        for (int j = 0; j < 4; ++j) {
            float s = 0.f;
#pragma unroll
            for (int n = 0; n < 4; ++n) {
                float e = valid[n] ? __expf(acc[m][n][j] - rmax[m][j]) : 0.f;
                acc[m][n][j] = e;
                s += e;
            }
#pragma unroll
            for (int off = 8; off >= 1; off >>= 1) s += __shfl_xor(s, off, 64);
            sum[m][j] = s;
        }
    if (fr == 0) {
#pragma unroll
        for (int m = 0; m < 4; ++m)
#pragma unroll
            for (int j = 0; j < 4; ++j) red[1][m * 16 + quad * 4 + j][w] = sum[m][j];
    }
    __syncthreads();
#pragma unroll
    for (int m = 0; m < 4; ++m)
#pragma unroll
        for (int j = 0; j < 4; ++j) {
            const int row = m * 16 + quad * 4 + j;
            float s = 0.f;
#pragma unroll
            for (int ww = 0; ww < 8; ++ww) s += red[1][row][ww];
            const float inv = 1.f / s;
#pragma unroll
            for (int n = 0; n < 4; ++n)
                P[(row0 + row) * 512 + w * 64 + n * 16 + fr] =
                    __float2bfloat16(acc[m][n][j] * inv);
        }
}

extern "C" void kernel_launch(void* const* d_in, const int* in_sizes, int n_in,
                              void* d_out, int out_size, void* d_ws, size_t ws_size,
                              hipStream_t stream) {
    const float* X = (const float*)d_in[0];
    const int* sen = (const int*)d_in[1];
    const float* W = (const float*)d_in[2];
    const float* bias = (const float*)d_in[3];
    const float* U = (const float*)d_in[4];
    float* out = (float*)d_out;

    const int B = 64, T = 512, H = 1024, A = 256;
    const long M = (long)B * T;  // 32768

    // workspace: P (32Mi) | Wt (0.5Mi) | Ut (0.25Mi)
    char* ws = (char*)d_ws;
    __hip_bfloat16* Pbf = (__hip_bfloat16*)ws;
    __hip_bfloat16* Wt = (__hip_bfloat16*)(ws + M * T * 2);
    __hip_bfloat16* Ut = (__hip_bfloat16*)((char*)Wt + (long)H * A * 2);

    // d_out scratch: alpha bf16 at [64Mi,80Mi) — consumed by score_softmax
    // before gemm_pv overwrites all of d_out with Z.
    __hip_bfloat16* alpha = (__hip_bfloat16*)((char*)d_out + M * H * 2);

    // 1. W^T [A][H], U^T [T][A]
    transpose_cvt_kernel<<<(H * A) / 256, 256, 0, stream>>>(W, Wt, H, A);
    transpose_cvt_kernel<<<(A * T) / 256, 256, 0, stream>>>(U, Ut, A, T);
    // 2. alpha = tanh(X*W + b) — r11 v2 (measured-best)
    gemm_xw_kernel<<<dim3(2, 256), 512, 0, stream>>>(X, Wt, alpha, bias);
    // 3. P = softmax(alpha * U^T, mask) — barrier-free K-loop
    score_softmax_kernel<<<(int)(M / 64), 512, 0, stream>>>(alpha, Ut, Pbf, sen);
    // 4. Z = P * X — v9: v5 schedule + chunk-XOR swizzle (conflict fix A/B)
    gemm_pv_kernel<<<dim3(H / 128, T / 256, B), 512, 0, stream>>>(Pbf, X, out);
}

// Round 16
// 136.689 us; speedup vs baseline: 1.2504x; 1.0885x over previous
//
#include <hip/hip_runtime.h>
#include <hip/hip_bf16.h>

typedef short short8 __attribute__((ext_vector_type(8)));
typedef short short4v __attribute__((ext_vector_type(4)));
typedef float f32x4 __attribute__((ext_vector_type(4)));
typedef __bf16 bf16x8 __attribute__((ext_vector_type(8)));

// ---- stage a ROWSx64 bf16 tile via global_load_lds, 16B-chunk XOR swizzle --
template <int ROWS>
__device__ __forceinline__ void stage2(const __hip_bfloat16* __restrict__ g,
                                       int ld, short* lds, int t) {
    const int w = t >> 6;
    const int lane = t & 63;
#pragma unroll
    for (int i = 0; i < ROWS / 64; ++i) {
        const int cb = i * 512 + w * 64;     // wave-uniform chunk base
        const int c = cb + lane;
        const int row = c >> 3;
        const int kc = (c & 7) ^ (row & 7);
        __builtin_amdgcn_global_load_lds((const void*)(g + (long)row * ld + kc * 8),
                                         (void*)(lds + cb * 8), 16, 0, 0);
    }
}

// -------- gemm_xw (r11 v2 + group swizzle): alpha = tanh(X*Wt^T + b) --------
// BM=128(t) x BN=128(a) x BK=64(h), K=1024. Grid (2,256)=512 wgs, 8 waves.
// GROUP SWIZZLE: both bx blocks of a row-group (shared 512KB X panel, shared
// alpha rows) drawn from the same XCD chunk: xcd=lin&7, by=xcd*32+(idx>>1),
// bx=idx&1 (bijective).
__global__ __launch_bounds__(512, 4) void gemm_xw_kernel(
    const float* __restrict__ Xf,           // [32768][1024]
    const __hip_bfloat16* __restrict__ Wt,  // [256][1024]
    __hip_bfloat16* __restrict__ alpha,     // [32768][256]
    const float* __restrict__ bias) {
    __shared__ __align__(16) short smB[3][8192];   // 16KB x3 (Wt tiles)
    __shared__ __align__(16) short smA[2][8192];   // 16KB x2 (X tiles, bf16)

    int bx, by;
    {
        const int lin = blockIdx.x + 2 * blockIdx.y;  // [0,512)
        const int xcd = lin & 7;
        const int idx = lin >> 3;                     // [0,64)
        by = xcd * 32 + (idx >> 1);                   // [0,256)
        bx = idx & 1;
    }

    const int t = threadIdx.x;
    const int w = t >> 6, lane = t & 63;
    const int wm = w >> 1, wn = w & 1;   // 4 x 2 waves
    const int fr = lane & 15, quad = lane >> 4;

    const float* Ab = Xf + (long)by * 128 * 1024;
    const __hip_bfloat16* Bb = Wt + (long)bx * 128 * 1024;

    int acs[2], arow[2], akc[2];
#pragma unroll
    for (int i = 0; i < 2; ++i) {
        acs[i] = i * 512 + t;
        arow[i] = acs[i] >> 3;
        akc[i] = ((acs[i] & 7) ^ (arow[i] & 7)) * 8;
    }

    f32x4 acc[2][4] = {};
    float4 rA[2][2];

#define XW_ISSUE_B(KT, BUF) stage2<128>(Bb + (KT) * 64, 1024, &smB[BUF][0], t);

#define XW_LOAD_A(KT)                                                           \
    _Pragma("unroll") for (int i = 0; i < 2; ++i) {                             \
        const float* src = Ab + (long)arow[i] * 1024 + (KT) * 64 + akc[i];      \
        rA[i][0] = *(const float4*)(src);                                       \
        rA[i][1] = *(const float4*)(src + 4);                                   \
    }

#define XW_WRITE_A(BUF)                                                         \
    _Pragma("unroll") for (int i = 0; i < 2; ++i) {                             \
        __hip_bfloat16 tmp[8] __attribute__((aligned(16)));                     \
        tmp[0] = __float2bfloat16(rA[i][0].x);                                  \
        tmp[1] = __float2bfloat16(rA[i][0].y);                                  \
        tmp[2] = __float2bfloat16(rA[i][0].z);                                  \
        tmp[3] = __float2bfloat16(rA[i][0].w);                                  \
        tmp[4] = __float2bfloat16(rA[i][1].x);                                  \
        tmp[5] = __float2bfloat16(rA[i][1].y);                                  \
        tmp[6] = __float2bfloat16(rA[i][1].z);                                  \
        tmp[7] = __float2bfloat16(rA[i][1].w);                                  \
        *(short8*)(void*)&smA[BUF][acs[i] * 8] = *(short8*)(void*)tmp;          \
    }

    XW_ISSUE_B(0, 0)
    XW_ISSUE_B(1, 1)
    XW_LOAD_A(0)
    XW_WRITE_A(0)          // auto-waits on A(0) regs
    XW_LOAD_A(1)
    __builtin_amdgcn_sched_barrier(0);
    asm volatile("s_waitcnt vmcnt(4)" ::: "memory");
    asm volatile("s_waitcnt lgkmcnt(0)" ::: "memory");
    __builtin_amdgcn_s_barrier();
    __builtin_amdgcn_sched_barrier(0);

#pragma unroll
    for (int k = 0; k < 16; ++k) {
        if (k + 2 < 16) XW_ISSUE_B(k + 2, (k + 2) % 3)
        {
            const short* At = &smA[k % 2][0];
            const short* Bt = &smB[k % 3][0];
#pragma unroll
            for (int ks = 0; ks < 2; ++ks) {
                bf16x8 af[2], bfv[4];
                const int kc = ks * 4 + quad;
#pragma unroll
                for (int m = 0; m < 2; ++m) {
                    const int row = wm * 32 + m * 16 + fr;
                    const int chunk = row * 8 + (kc ^ (row & 7));
                    af[m] = *(const bf16x8*)(const void*)(At + chunk * 8);
                }
#pragma unroll
                for (int n = 0; n < 4; ++n) {
                    const int row = wn * 64 + n * 16 + fr;
                    const int chunk = row * 8 + (kc ^ (row & 7));
                    bfv[n] = *(const bf16x8*)(const void*)(Bt + chunk * 8);
                }
#pragma unroll
                for (int m = 0; m < 2; ++m)
#pragma unroll
                    for (int n = 0; n < 4; ++n)
                        acc[m][n] = __builtin_amdgcn_mfma_f32_16x16x32_bf16(
                            af[m], bfv[n], acc[m][n], 0, 0, 0);
            }
        }
        if (k + 1 < 16) XW_WRITE_A((k + 1) % 2)   // auto-waits on A(k+1) regs
        if (k + 2 < 16) XW_LOAD_A(k + 2)
        __builtin_amdgcn_sched_barrier(0);
        if (k + 2 < 16) {
            asm volatile("s_waitcnt vmcnt(6)" ::: "memory");
        } else if (k + 1 < 16) {
            asm volatile("s_waitcnt vmcnt(0)" ::: "memory");
        }
        if (k + 1 < 16) {
            asm volatile("s_waitcnt lgkmcnt(0)" ::: "memory");
            __builtin_amdgcn_s_barrier();
            __builtin_amdgcn_sched_barrier(0);
        }
    }
#undef XW_ISSUE_B
#undef XW_LOAD_A
#undef XW_WRITE_A

    const long rowBase = (long)by * 128 + wm * 32;
    const int colBase = bx * 128 + wn * 64;
#pragma unroll
    for (int m = 0; m < 2; ++m) {
#pragma unroll
        for (int n = 0; n < 4; ++n) {
            const int col = colBase + n * 16 + fr;
            const float bv = bias[col];
#pragma unroll
            for (int j = 0; j < 4; ++j) {
                const long row = rowBase + m * 16 + quad * 4 + j;
                alpha[row * 256 + col] = __float2bfloat16(tanhf(acc[m][n][j] + bv));
            }
        }
    }
}

// -------- gemm_pv v10: r10-best structure + GROUP swizzle ------------------
// Tile 256t x 128h x BK=32s, K=512. A (P bf16): glds slot-XOR, TRIPLE-buf;
// B (X f32): reg-staged transposed (r9-verified layout), double-buf LDS.
// GROUP SWIZZLE: all 8 bx blocks of a (by,bz) group (shared 256KB P panel;
// Z rows written WHOLE within one XCD) drawn from one XCD chunk:
// xcd=lin&7, idx=lin>>3; grp=xcd*16+(idx>>3), bx=idx&7 (bijective).
__global__ __launch_bounds__(512, 4) void gemm_pv_kernel(
    const __hip_bfloat16* __restrict__ P,  // [B*512][512]
    const float* __restrict__ Xf,          // [B*512][1024]
    float* __restrict__ Z) {               // [B*512][1024]
    __shared__ __align__(16) short smA[3][8192];   // 16KB x3
    __shared__ __align__(16) short smB[2][5120];   // 10KB x2

    int bx, by, bz;
    {
        const int lin = blockIdx.x + 8 * (blockIdx.y + 2 * blockIdx.z);  // [0,1024)
        const int xcd = lin & 7;
        const int idx = lin >> 3;                 // [0,128)
        const int grp = xcd * 16 + (idx >> 3);    // [0,128) = (by,bz) group
        bx = idx & 7;
        by = grp & 1;
        bz = grp >> 1;
    }

    const int t = threadIdx.x;
    const int w = t >> 6, lane = t & 63;
    const int wm = w >> 1, wn = w & 1;   // 4 x 2 waves
    const int fr = lane & 15, quad = lane >> 4;

    const __hip_bfloat16* Ab = P + ((long)bz * 512 + by * 256) * 512;
    const float* Bb = Xf + (long)bz * 512 * 1024 + bx * 128;

    // A staging slots (2 granules per thread) — r9-verified mapping
    int acb[2], arow[2], akc[2];
#pragma unroll
    for (int i = 0; i < 2; ++i) {
        acb[i] = i * 512 + w * 64;           // wave-uniform
        const int s = acb[i] + lane;
        arow[i] = s >> 2;
        akc[i] = ((s & 3) ^ ((arow[i] >> 1) & 3)) * 8;
    }
    // B thread mapping: s-pair (2bi, 2bi+1), h = bhc*4 + j
    const int bi = t & 15;
    const int bhc = t >> 4;   // 0..31

    f32x4 acc[4][4] = {};
    float4 r0, r1;

#define PV_ISSUE_A(KT, BUF)                                                     \
    _Pragma("unroll") for (int i = 0; i < 2; ++i)                               \
        __builtin_amdgcn_global_load_lds(                                       \
            (const void*)(Ab + (long)arow[i] * 512 + (KT) * 32 + akc[i]),       \
            (void*)(&smA[BUF][acb[i] * 8]), 16, 0, 0);

#define PV_LOAD_B(KT)                                                           \
    {                                                                           \
        const float* s0 = Bb + (long)((KT) * 32 + 2 * bi) * 1024 + bhc * 4;     \
        r0 = *(const float4*)(s0);                                              \
        r1 = *(const float4*)(s0 + 1024);                                       \
    }

#define PV_WRITE_B(BUF)                                                         \
    {                                                                           \
        int* dst = (int*)(void*)&smB[BUF][(bhc * 4) * 40 + bi * 2];             \
        _Pragma("unroll") for (int j = 0; j < 4; ++j) {                         \
            __hip_bfloat16 h0 = __float2bfloat16(((const float*)&r0)[j]);       \
            __hip_bfloat16 h1 = __float2bfloat16(((const float*)&r1)[j]);       \
            dst[j * 20] = (int)*(unsigned short*)&h0 |                          \
                          ((int)*(unsigned short*)&h1 << 16);                   \
        }                                                                       \
    }

    // ---- prologue: A(0)->buf0, A(1)->buf1, B(0) staged, B(1) in regs ----
    PV_ISSUE_A(0, 0)
    PV_ISSUE_A(1, 1)
    PV_LOAD_B(0)
    PV_WRITE_B(0)          // compiler auto-waits on B(0) regs
    PV_LOAD_B(1)
    __builtin_amdgcn_sched_barrier(0);
    asm volatile("s_waitcnt vmcnt(4)" ::: "memory");   // A(0) landed
    asm volatile("s_waitcnt lgkmcnt(0)" ::: "memory"); // B(0) LDS visible
    __builtin_amdgcn_s_barrier();
    __builtin_amdgcn_sched_barrier(0);

#pragma unroll
    for (int k = 0; k < 16; ++k) {
        if (k + 2 < 16) PV_ISSUE_A(k + 2, (k + 2) % 3)
        // ---- compute from smA[k%3], smB[k%2] ----
        {
            const short* At = &smA[k % 3][0];
            const short* Bt = &smB[k % 2][0];
            bf16x8 bfv[4];
#pragma unroll
            for (int n = 0; n < 4; ++n) {
                const int h = wn * 64 + n * 16 + fr;
                bfv[n] = *(const bf16x8*)(const void*)(Bt + h * 40 + quad * 8);
            }
#pragma unroll
            for (int m = 0; m < 4; ++m) {
                const int row = wm * 64 + m * 16 + fr;
                const int slot = row * 4 + (quad ^ ((row >> 1) & 3));
                const bf16x8 af = *(const bf16x8*)(const void*)(At + slot * 8);
#pragma unroll
                for (int n = 0; n < 4; ++n)
                    acc[m][n] = __builtin_amdgcn_mfma_f32_16x16x32_bf16(
                        af, bfv[n], acc[m][n], 0, 0, 0);
            }
        }
        if (k + 1 < 16) PV_WRITE_B((k + 1) % 2)   // auto-waits on B(k+1) regs
        if (k + 2 < 16) PV_LOAD_B(k + 2)
        __builtin_amdgcn_sched_barrier(0);
        if (k + 2 < 16) {
            asm volatile("s_waitcnt vmcnt(4)" ::: "memory");
        } else if (k + 1 < 16) {
            asm volatile("s_waitcnt vmcnt(0)" ::: "memory");
        }
        if (k + 1 < 16) {
            asm volatile("s_waitcnt lgkmcnt(0)" ::: "memory");
            __builtin_amdgcn_s_barrier();
            __builtin_amdgcn_sched_barrier(0);
        }
    }
#undef PV_ISSUE_A
#undef PV_LOAD_B
#undef PV_WRITE_B

    // epilogue: C/D layout col = lane&15, row = (lane>>4)*4 + j
    const long rowBase = (long)bz * 512 + by * 256 + wm * 64;
    const int colBase = bx * 128 + wn * 64;
#pragma unroll
    for (int m = 0; m < 4; ++m) {
#pragma unroll
        for (int n = 0; n < 4; ++n) {
            const int col = colBase + n * 16 + fr;
#pragma unroll
            for (int j = 0; j < 4; ++j) {
                const long row = rowBase + m * 16 + quad * 4 + j;
                Z[row * 1024 + col] = acc[m][n][j];
            }
        }
    }
}

// naive small transpose+convert: in [R][C] f32 -> out [C][R] bf16
__global__ __launch_bounds__(256) void transpose_cvt_kernel(const float* __restrict__ in,
                                                            __hip_bfloat16* __restrict__ out,
                                                            int R, int C) {
    const int o = blockIdx.x * 256 + threadIdx.x;
    if (o >= R * C) return;
    const int c = o / R;
    const int r = o - c * R;
    out[o] = __float2bfloat16(in[(long)r * C + c]);
}

// -------- score_softmax v2: barrier-free K-loop (r12, unchanged) -----------
__global__ __launch_bounds__(512, 4) void score_softmax_kernel(
    const __hip_bfloat16* __restrict__ Aa,  // alpha [32768][256]
    const __hip_bfloat16* __restrict__ Ut,  // [512][256]
    __hip_bfloat16* __restrict__ P,         // [32768][512]
    const int* __restrict__ sen) {
    __shared__ __align__(16) short At[2048 * 8];   // 32KB
    __shared__ float red[2][64][9];

    const int t = threadIdx.x;
    const int w = t >> 6, lane = t & 63;
    const int fr = lane & 15, quad = lane >> 4;
    const long row0 = (long)blockIdx.x * 64;
    const __hip_bfloat16* Ab = Aa + row0 * 256;

#pragma unroll
    for (int i = 0; i < 4; ++i) {
        const int cb = i * 512 + w * 64;
        const int c = cb + lane;
        const int row = c >> 5;
        const int kc = (c & 31) ^ (row & 7);
        __builtin_amdgcn_global_load_lds(
            (const void*)(Ab + (long)row * 256 + kc * 8),
            (void*)(At + cb * 8), 16, 0, 0);
    }

    f32x4 acc[4][4] = {};
    bf16x8 bfvs[2][4];

#define SM_LOAD_B(KT, S)                                                        \
    _Pragma("unroll") for (int n = 0; n < 4; ++n)                               \
        bfvs[S][n] = *(const bf16x8*)(const void*)(                             \
            Ut + (w * 64 + n * 16 + fr) * 256 + (KT) * 32 + quad * 8);

    SM_LOAD_B(0, 0)
    SM_LOAD_B(1, 1)
    __builtin_amdgcn_sched_barrier(0);
    asm volatile("s_waitcnt vmcnt(8)" ::: "memory");
    __builtin_amdgcn_s_barrier();
    __builtin_amdgcn_sched_barrier(0);

#define SM_STEP(KT)                                                             \
    {                                                                           \
        bf16x8 af[4];                                                           \
        _Pragma("unroll") for (int m = 0; m < 4; ++m) {                         \
            const int row = m * 16 + fr;                                        \
            const int g = row * 32 + (((KT) * 4 + quad) ^ (row & 7));           \
            af[m] = *(const bf16x8*)(const void*)(At + g * 8);                  \
        }                                                                       \
        _Pragma("unroll") for (int m = 0; m < 4; ++m)                           \
            _Pragma("unroll") for (int n = 0; n < 4; ++n)                       \
                acc[m][n] = __builtin_amdgcn_mfma_f32_16x16x32_bf16(            \
                    af[m], bfvs[(KT) & 1][n], acc[m][n], 0, 0, 0);              \
        if ((KT) + 2 < 8) { SM_LOAD_B((KT) + 2, (KT) & 1) }                     \
    }

    SM_STEP(0) SM_STEP(1) SM_STEP(2) SM_STEP(3)
    SM_STEP(4) SM_STEP(5) SM_STEP(6) SM_STEP(7)
#undef SM_STEP
#undef SM_LOAD_B
    __syncthreads();

    const int L = sen[row0 >> 9];
    bool valid[4];
#pragma unroll
    for (int n = 0; n < 4; ++n) valid[n] = (w * 64 + n * 16 + fr) < L;

    float mx[4][4];
#pragma unroll
    for (int m = 0; m < 4; ++m)
#pragma unroll
        for (int j = 0; j < 4; ++j) {
            float v = -3.0e38f;
#pragma unroll
            for (int n = 0; n < 4; ++n)
                if (valid[n]) v = fmaxf(v, acc[m][n][j]);
#pragma unroll
            for (int off = 8; off >= 1; off >>= 1) v = fmaxf(v, __shfl_xor(v, off, 64));
            mx[m][j] = v;
        }
    if (fr == 0) {
#pragma unroll
        for (int m = 0; m < 4; ++m)
#pragma unroll
            for (int j = 0; j < 4; ++j) red[0][m * 16 + quad * 4 + j][w] = mx[m][j];
    }
    __syncthreads();
    float rmax[4][4];
#pragma unroll
    for (int m = 0; m < 4; ++m)
#pragma unroll
        for (int j = 0; j < 4; ++j) {
            const int row = m * 16 + quad * 4 + j;
            float v = red[0][row][0];
#pragma unroll
            for (int ww = 1; ww < 8; ++ww) v = fmaxf(v, red[0][row][ww]);
            rmax[m][j] = v;
        }

    float sum[4][4];
#pragma unroll
    for (int m = 0; m < 4; ++m)
#pragma unroll
        for (int j = 0; j < 4; ++j) {
            float s = 0.f;
#pragma unroll
            for (int n = 0; n < 4; ++n) {
                float e = valid[n] ? __expf(acc[m][n][j] - rmax[m][j]) : 0.f;
                acc[m][n][j] = e;
                s += e;
            }
#pragma unroll
            for (int off = 8; off >= 1; off >>= 1) s += __shfl_xor(s, off, 64);
            sum[m][j] = s;
        }
    if (fr == 0) {
#pragma unroll
        for (int m = 0; m < 4; ++m)
#pragma unroll
            for (int j = 0; j < 4; ++j) red[1][m * 16 + quad * 4 + j][w] = sum[m][j];
    }
    __syncthreads();
#pragma unroll
    for (int m = 0; m < 4; ++m)
#pragma unroll
        for (int j = 0; j < 4; ++j) {
            const int row = m * 16 + quad * 4 + j;
            float s = 0.f;
#pragma unroll
            for (int ww = 0; ww < 8; ++ww) s += red[1][row][ww];
            const float inv = 1.f / s;
#pragma unroll
            for (int n = 0; n < 4; ++n)
                P[(row0 + row) * 512 + w * 64 + n * 16 + fr] =
                    __float2bfloat16(acc[m][n][j] * inv);
        }
}

extern "C" void kernel_launch(void* const* d_in, const int* in_sizes, int n_in,
                              void* d_out, int out_size, void* d_ws, size_t ws_size,
                              hipStream_t stream) {
    const float* X = (const float*)d_in[0];
    const int* sen = (const int*)d_in[1];
    const float* W = (const float*)d_in[2];
    const float* bias = (const float*)d_in[3];
    const float* U = (const float*)d_in[4];
    float* out = (float*)d_out;

    const int B = 64, T = 512, H = 1024, A = 256;
    const long M = (long)B * T;  // 32768

    // workspace: P (32Mi) | Wt (0.5Mi) | Ut (0.25Mi)
    char* ws = (char*)d_ws;
    __hip_bfloat16* Pbf = (__hip_bfloat16*)ws;
    __hip_bfloat16* Wt = (__hip_bfloat16*)(ws + M * T * 2);
    __hip_bfloat16* Ut = (__hip_bfloat16*)((char*)Wt + (long)H * A * 2);

    // d_out scratch: alpha bf16 at [64Mi,80Mi) — consumed by score_softmax
    // before gemm_pv overwrites all of d_out with Z.
    __hip_bfloat16* alpha = (__hip_bfloat16*)((char*)d_out + M * H * 2);

    // 1. W^T [A][H], U^T [T][A]
    transpose_cvt_kernel<<<(H * A) / 256, 256, 0, stream>>>(W, Wt, H, A);
    transpose_cvt_kernel<<<(A * T) / 256, 256, 0, stream>>>(U, Ut, A, T);
    // 2. alpha = tanh(X*W + b) — r11-best + group swizzle
    gemm_xw_kernel<<<dim3(2, 256), 512, 0, stream>>>(X, Wt, alpha, bias);
    // 3. P = softmax(alpha * U^T, mask) — barrier-free K-loop
    score_softmax_kernel<<<(int)(M / 64), 512, 0, stream>>>(alpha, Ut, Pbf, sen);
    // 4. Z = P * X — r10-best structure + group swizzle (Z rows stay on-XCD)
    gemm_pv_kernel<<<dim3(H / 128, T / 256, B), 512, 0, stream>>>(Pbf, X, out);
}

// Round 17
// 135.246 us; speedup vs baseline: 1.2638x; 1.0107x over previous
//
#include <hip/hip_runtime.h>
#include <hip/hip_bf16.h>

typedef short short8 __attribute__((ext_vector_type(8)));
typedef short short4v __attribute__((ext_vector_type(4)));
typedef float f32x4 __attribute__((ext_vector_type(4)));
typedef __bf16 bf16x8 __attribute__((ext_vector_type(8)));

// ---- stage a ROWSx64 bf16 tile via global_load_lds, 16B-chunk XOR swizzle --
template <int ROWS>
__device__ __forceinline__ void stage2(const __hip_bfloat16* __restrict__ g,
                                       int ld, short* lds, int t) {
    const int w = t >> 6;
    const int lane = t & 63;
#pragma unroll
    for (int i = 0; i < ROWS / 64; ++i) {
        const int cb = i * 512 + w * 64;     // wave-uniform chunk base
        const int c = cb + lane;
        const int row = c >> 3;
        const int kc = (c & 7) ^ (row & 7);
        __builtin_amdgcn_global_load_lds((const void*)(g + (long)row * ld + kc * 8),
                                         (void*)(lds + cb * 8), 16, 0, 0);
    }
}

// -------- gemm_xw (r16 + T5 setprio): alpha = tanh(X*Wt^T + b) --------------
__global__ __launch_bounds__(512, 4) void gemm_xw_kernel(
    const float* __restrict__ Xf,           // [32768][1024]
    const __hip_bfloat16* __restrict__ Wt,  // [256][1024]
    __hip_bfloat16* __restrict__ alpha,     // [32768][256]
    const float* __restrict__ bias) {
    __shared__ __align__(16) short smB[3][8192];   // 16KB x3 (Wt tiles)
    __shared__ __align__(16) short smA[2][8192];   // 16KB x2 (X tiles, bf16)

    int bx, by;
    {   // group swizzle: both bx of a row-group on one XCD (r16-verified)
        const int lin = blockIdx.x + 2 * blockIdx.y;  // [0,512)
        const int xcd = lin & 7;
        const int idx = lin >> 3;                     // [0,64)
        by = xcd * 32 + (idx >> 1);                   // [0,256)
        bx = idx & 1;
    }

    const int t = threadIdx.x;
    const int w = t >> 6, lane = t & 63;
    const int wm = w >> 1, wn = w & 1;   // 4 x 2 waves
    const int fr = lane & 15, quad = lane >> 4;

    const float* Ab = Xf + (long)by * 128 * 1024;
    const __hip_bfloat16* Bb = Wt + (long)bx * 128 * 1024;

    int acs[2], arow[2], akc[2];
#pragma unroll
    for (int i = 0; i < 2; ++i) {
        acs[i] = i * 512 + t;
        arow[i] = acs[i] >> 3;
        akc[i] = ((acs[i] & 7) ^ (arow[i] & 7)) * 8;
    }

    f32x4 acc[2][4] = {};
    float4 rA[2][2];

#define XW_ISSUE_B(KT, BUF) stage2<128>(Bb + (KT) * 64, 1024, &smB[BUF][0], t);

#define XW_LOAD_A(KT)                                                           \
    _Pragma("unroll") for (int i = 0; i < 2; ++i) {                             \
        const float* src = Ab + (long)arow[i] * 1024 + (KT) * 64 + akc[i];      \
        rA[i][0] = *(const float4*)(src);                                       \
        rA[i][1] = *(const float4*)(src + 4);                                   \
    }

#define XW_WRITE_A(BUF)                                                         \
    _Pragma("unroll") for (int i = 0; i < 2; ++i) {                             \
        __hip_bfloat16 tmp[8] __attribute__((aligned(16)));                     \
        tmp[0] = __float2bfloat16(rA[i][0].x);                                  \
        tmp[1] = __float2bfloat16(rA[i][0].y);                                  \
        tmp[2] = __float2bfloat16(rA[i][0].z);                                  \
        tmp[3] = __float2bfloat16(rA[i][0].w);                                  \
        tmp[4] = __float2bfloat16(rA[i][1].x);                                  \
        tmp[5] = __float2bfloat16(rA[i][1].y);                                  \
        tmp[6] = __float2bfloat16(rA[i][1].z);                                  \
        tmp[7] = __float2bfloat16(rA[i][1].w);                                  \
        *(short8*)(void*)&smA[BUF][acs[i] * 8] = *(short8*)(void*)tmp;          \
    }

    XW_ISSUE_B(0, 0)
    XW_ISSUE_B(1, 1)
    XW_LOAD_A(0)
    XW_WRITE_A(0)          // auto-waits on A(0) regs
    XW_LOAD_A(1)
    __builtin_amdgcn_sched_barrier(0);
    asm volatile("s_waitcnt vmcnt(4)" ::: "memory");
    asm volatile("s_waitcnt lgkmcnt(0)" ::: "memory");
    __builtin_amdgcn_s_barrier();
    __builtin_amdgcn_sched_barrier(0);

#pragma unroll
    for (int k = 0; k < 16; ++k) {
        if (k + 2 < 16) XW_ISSUE_B(k + 2, (k + 2) % 3)
        {
            const short* At = &smA[k % 2][0];
            const short* Bt = &smB[k % 3][0];
            __builtin_amdgcn_s_setprio(1);     // T5: favor MFMA-phase wave
#pragma unroll
            for (int ks = 0; ks < 2; ++ks) {
                bf16x8 af[2], bfv[4];
                const int kc = ks * 4 + quad;
#pragma unroll
                for (int m = 0; m < 2; ++m) {
                    const int row = wm * 32 + m * 16 + fr;
                    const int chunk = row * 8 + (kc ^ (row & 7));
                    af[m] = *(const bf16x8*)(const void*)(At + chunk * 8);
                }
#pragma unroll
                for (int n = 0; n < 4; ++n) {
                    const int row = wn * 64 + n * 16 + fr;
                    const int chunk = row * 8 + (kc ^ (row & 7));
                    bfv[n] = *(const bf16x8*)(const void*)(Bt + chunk * 8);
                }
#pragma unroll
                for (int m = 0; m < 2; ++m)
#pragma unroll
                    for (int n = 0; n < 4; ++n)
                        acc[m][n] = __builtin_amdgcn_mfma_f32_16x16x32_bf16(
                            af[m], bfv[n], acc[m][n], 0, 0, 0);
            }
            __builtin_amdgcn_s_setprio(0);
        }
        if (k + 1 < 16) XW_WRITE_A((k + 1) % 2)   // auto-waits on A(k+1) regs
        if (k + 2 < 16) XW_LOAD_A(k + 2)
        __builtin_amdgcn_sched_barrier(0);
        if (k + 2 < 16) {
            asm volatile("s_waitcnt vmcnt(6)" ::: "memory");
        } else if (k + 1 < 16) {
            asm volatile("s_waitcnt vmcnt(0)" ::: "memory");
        }
        if (k + 1 < 16) {
            asm volatile("s_waitcnt lgkmcnt(0)" ::: "memory");
            __builtin_amdgcn_s_barrier();
            __builtin_amdgcn_sched_barrier(0);
        }
    }
#undef XW_ISSUE_B
#undef XW_LOAD_A
#undef XW_WRITE_A

    const long rowBase = (long)by * 128 + wm * 32;
    const int colBase = bx * 128 + wn * 64;
#pragma unroll
    for (int m = 0; m < 2; ++m) {
#pragma unroll
        for (int n = 0; n < 4; ++n) {
            const int col = colBase + n * 16 + fr;
            const float bv = bias[col];
#pragma unroll
            for (int j = 0; j < 4; ++j) {
                const long row = rowBase + m * 16 + quad * 4 + j;
                alpha[row * 256 + col] = __float2bfloat16(tanhf(acc[m][n][j] + bv));
            }
        }
    }
}

// -------- gemm_pv v10 + T5 setprio ------------------------------------------
// Tile 256t x 128h x BK=32s. A (P bf16): glds slot-XOR, triple-buf;
// B (X f32): reg-staged transposed, double-buf LDS. Group swizzle (r16).
__global__ __launch_bounds__(512, 4) void gemm_pv_kernel(
    const __hip_bfloat16* __restrict__ P,  // [B*512][512]
    const float* __restrict__ Xf,          // [B*512][1024]
    float* __restrict__ Z) {               // [B*512][1024]
    __shared__ __align__(16) short smA[3][8192];   // 16KB x3
    __shared__ __align__(16) short smB[2][5120];   // 10KB x2

    int bx, by, bz;
    {
        const int lin = blockIdx.x + 8 * (blockIdx.y + 2 * blockIdx.z);  // [0,1024)
        const int xcd = lin & 7;
        const int idx = lin >> 3;                 // [0,128)
        const int grp = xcd * 16 + (idx >> 3);    // [0,128) = (by,bz) group
        bx = idx & 7;
        by = grp & 1;
        bz = grp >> 1;
    }

    const int t = threadIdx.x;
    const int w = t >> 6, lane = t & 63;
    const int wm = w >> 1, wn = w & 1;   // 4 x 2 waves
    const int fr = lane & 15, quad = lane >> 4;

    const __hip_bfloat16* Ab = P + ((long)bz * 512 + by * 256) * 512;
    const float* Bb = Xf + (long)bz * 512 * 1024 + bx * 128;

    int acb[2], arow[2], akc[2];
#pragma unroll
    for (int i = 0; i < 2; ++i) {
        acb[i] = i * 512 + w * 64;           // wave-uniform
        const int s = acb[i] + lane;
        arow[i] = s >> 2;
        akc[i] = ((s & 3) ^ ((arow[i] >> 1) & 3)) * 8;
    }
    const int bi = t & 15;
    const int bhc = t >> 4;   // 0..31

    f32x4 acc[4][4] = {};
    float4 r0, r1;

#define PV_ISSUE_A(KT, BUF)                                                     \
    _Pragma("unroll") for (int i = 0; i < 2; ++i)                               \
        __builtin_amdgcn_global_load_lds(                                       \
            (const void*)(Ab + (long)arow[i] * 512 + (KT) * 32 + akc[i]),       \
            (void*)(&smA[BUF][acb[i] * 8]), 16, 0, 0);

#define PV_LOAD_B(KT)                                                           \
    {                                                                           \
        const float* s0 = Bb + (long)((KT) * 32 + 2 * bi) * 1024 + bhc * 4;     \
        r0 = *(const float4*)(s0);                                              \
        r1 = *(const float4*)(s0 + 1024);                                       \
    }

#define PV_WRITE_B(BUF)                                                         \
    {                                                                           \
        int* dst = (int*)(void*)&smB[BUF][(bhc * 4) * 40 + bi * 2];             \
        _Pragma("unroll") for (int j = 0; j < 4; ++j) {                         \
            __hip_bfloat16 h0 = __float2bfloat16(((const float*)&r0)[j]);       \
            __hip_bfloat16 h1 = __float2bfloat16(((const float*)&r1)[j]);       \
            dst[j * 20] = (int)*(unsigned short*)&h0 |                          \
                          ((int)*(unsigned short*)&h1 << 16);                   \
        }                                                                       \
    }

    PV_ISSUE_A(0, 0)
    PV_ISSUE_A(1, 1)
    PV_LOAD_B(0)
    PV_WRITE_B(0)          // compiler auto-waits on B(0) regs
    PV_LOAD_B(1)
    __builtin_amdgcn_sched_barrier(0);
    asm volatile("s_waitcnt vmcnt(4)" ::: "memory");   // A(0) landed
    asm volatile("s_waitcnt lgkmcnt(0)" ::: "memory"); // B(0) LDS visible
    __builtin_amdgcn_s_barrier();
    __builtin_amdgcn_sched_barrier(0);

#pragma unroll
    for (int k = 0; k < 16; ++k) {
        if (k + 2 < 16) PV_ISSUE_A(k + 2, (k + 2) % 3)
        {
            const short* At = &smA[k % 3][0];
            const short* Bt = &smB[k % 2][0];
            bf16x8 bfv[4];
#pragma unroll
            for (int n = 0; n < 4; ++n) {
                const int h = wn * 64 + n * 16 + fr;
                bfv[n] = *(const bf16x8*)(const void*)(Bt + h * 40 + quad * 8);
            }
            __builtin_amdgcn_s_setprio(1);     // T5: favor MFMA-phase wave
#pragma unroll
            for (int m = 0; m < 4; ++m) {
                const int row = wm * 64 + m * 16 + fr;
                const int slot = row * 4 + (quad ^ ((row >> 1) & 3));
                const bf16x8 af = *(const bf16x8*)(const void*)(At + slot * 8);
#pragma unroll
                for (int n = 0; n < 4; ++n)
                    acc[m][n] = __builtin_amdgcn_mfma_f32_16x16x32_bf16(
                        af, bfv[n], acc[m][n], 0, 0, 0);
            }
            __builtin_amdgcn_s_setprio(0);
        }
        if (k + 1 < 16) PV_WRITE_B((k + 1) % 2)   // auto-waits on B(k+1) regs
        if (k + 2 < 16) PV_LOAD_B(k + 2)
        __builtin_amdgcn_sched_barrier(0);
        if (k + 2 < 16) {
            asm volatile("s_waitcnt vmcnt(4)" ::: "memory");
        } else if (k + 1 < 16) {
            asm volatile("s_waitcnt vmcnt(0)" ::: "memory");
        }
        if (k + 1 < 16) {
            asm volatile("s_waitcnt lgkmcnt(0)" ::: "memory");
            __builtin_amdgcn_s_barrier();
            __builtin_amdgcn_sched_barrier(0);
        }
    }
#undef PV_ISSUE_A
#undef PV_LOAD_B
#undef PV_WRITE_B

    const long rowBase = (long)bz * 512 + by * 256 + wm * 64;
    const int colBase = bx * 128 + wn * 64;
#pragma unroll
    for (int m = 0; m < 4; ++m) {
#pragma unroll
        for (int n = 0; n < 4; ++n) {
            const int col = colBase + n * 16 + fr;
#pragma unroll
            for (int j = 0; j < 4; ++j) {
                const long row = rowBase + m * 16 + quad * 4 + j;
                Z[row * 1024 + col] = acc[m][n][j];
            }
        }
    }
}

// naive small transpose+convert: in [R][C] f32 -> out [C][R] bf16
__global__ __launch_bounds__(256) void transpose_cvt_kernel(const float* __restrict__ in,
                                                            __hip_bfloat16* __restrict__ out,
                                                            int R, int C) {
    const int o = blockIdx.x * 256 + threadIdx.x;
    if (o >= R * C) return;
    const int c = o / R;
    const int r = o - c * R;
    out[o] = __float2bfloat16(in[(long)r * C + c]);
}

// -------- score_softmax v2: barrier-free K-loop (r12, unchanged) -----------
__global__ __launch_bounds__(512, 4) void score_softmax_kernel(
    const __hip_bfloat16* __restrict__ Aa,  // alpha [32768][256]
    const __hip_bfloat16* __restrict__ Ut,  // [512][256]
    __hip_bfloat16* __restrict__ P,         // [32768][512]
    const int* __restrict__ sen) {
    __shared__ __align__(16) short At[2048 * 8];   // 32KB
    __shared__ float red[2][64][9];

    const int t = threadIdx.x;
    const int w = t >> 6, lane = t & 63;
    const int fr = lane & 15, quad = lane >> 4;
    const long row0 = (long)blockIdx.x * 64;
    const __hip_bfloat16* Ab = Aa + row0 * 256;

#pragma unroll
    for (int i = 0; i < 4; ++i) {
        const int cb = i * 512 + w * 64;
        const int c = cb + lane;
        const int row = c >> 5;
        const int kc = (c & 31) ^ (row & 7);
        __builtin_amdgcn_global_load_lds(
            (const void*)(Ab + (long)row * 256 + kc * 8),
            (void*)(At + cb * 8), 16, 0, 0);
    }

    f32x4 acc[4][4] = {};
    bf16x8 bfvs[2][4];

#define SM_LOAD_B(KT, S)                                                        \
    _Pragma("unroll") for (int n = 0; n < 4; ++n)                               \
        bfvs[S][n] = *(const bf16x8*)(const void*)(                             \
            Ut + (w * 64 + n * 16 + fr) * 256 + (KT) * 32 + quad * 8);

    SM_LOAD_B(0, 0)
    SM_LOAD_B(1, 1)
    __builtin_amdgcn_sched_barrier(0);
    asm volatile("s_waitcnt vmcnt(8)" ::: "memory");
    __builtin_amdgcn_s_barrier();
    __builtin_amdgcn_sched_barrier(0);

#define SM_STEP(KT)                                                             \
    {                                                                           \
        bf16x8 af[4];                                                           \
        _Pragma("unroll") for (int m = 0; m < 4; ++m) {                         \
            const int row = m * 16 + fr;                                        \
            const int g = row * 32 + (((KT) * 4 + quad) ^ (row & 7));           \
            af[m] = *(const bf16x8*)(const void*)(At + g * 8);                  \
        }                                                                       \
        _Pragma("unroll") for (int m = 0; m < 4; ++m)                           \
            _Pragma("unroll") for (int n = 0; n < 4; ++n)                       \
                acc[m][n] = __builtin_amdgcn_mfma_f32_16x16x32_bf16(            \
                    af[m], bfvs[(KT) & 1][n], acc[m][n], 0, 0, 0);              \
        if ((KT) + 2 < 8) { SM_LOAD_B((KT) + 2, (KT) & 1) }                     \
    }

    SM_STEP(0) SM_STEP(1) SM_STEP(2) SM_STEP(3)
    SM_STEP(4) SM_STEP(5) SM_STEP(6) SM_STEP(7)
#undef SM_STEP
#undef SM_LOAD_B
    __syncthreads();

    const int L = sen[row0 >> 9];
    bool valid[4];
#pragma unroll
    for (int n = 0; n < 4; ++n) valid[n] = (w * 64 + n * 16 + fr) < L;

    float mx[4][4];
#pragma unroll
    for (int m = 0; m < 4; ++m)
#pragma unroll
        for (int j = 0; j < 4; ++j) {
            float v = -3.0e38f;
#pragma unroll
            for (int n = 0; n < 4; ++n)
                if (valid[n]) v = fmaxf(v, acc[m][n][j]);
#pragma unroll
            for (int off = 8; off >= 1; off >>= 1) v = fmaxf(v, __shfl_xor(v, off, 64));
            mx[m][j] = v;
        }
    if (fr == 0) {
#pragma unroll
        for (int m = 0; m < 4; ++m)
#pragma unroll
            for (int j = 0; j < 4; ++j) red[0][m * 16 + quad * 4 + j][w] = mx[m][j];
    }
    __syncthreads();
    float rmax[4][4];
#pragma unroll
    for (int m = 0; m < 4; ++m)
#pragma unroll
        for (int j = 0; j < 4; ++j) {
            const int row = m * 16 + quad * 4 + j;
            float v = red[0][row][0];
#pragma unroll
            for (int ww = 1; ww < 8; ++ww) v = fmaxf(v, red[0][row][ww]);
            rmax[m][j] = v;
        }

    float sum[4][4];
#pragma unroll
    for (int m = 0; m < 4; ++m)
#pragma unroll
        for (int j = 0; j < 4; ++j) {
            float s = 0.f;
#pragma unroll
            for (int n = 0; n < 4; ++n) {
                float e = valid[n] ? __expf(acc[m][n][j] - rmax[m][j]) : 0.f;
                acc[m][n][j] = e;
                s += e;
            }
#pragma unroll
            for (int off = 8; off >= 1; off >>= 1) s += __shfl_xor(s, off, 64);
            sum[m][j] = s;
        }
    if (fr == 0) {
#pragma unroll
        for (int m = 0; m < 4; ++m)
#pragma unroll
            for (int j = 0; j < 4; ++j) red[1][m * 16 + quad * 4 + j][w] = sum[m][j];
    }
    __syncthreads();
#pragma unroll
    for (int m = 0; m < 4; ++m)
#pragma unroll
        for (int j = 0; j < 4; ++j) {
            const int row = m * 16 + quad * 4 + j;
            float s = 0.f;
#pragma unroll
            for (int ww = 0; ww < 8; ++ww) s += red[1][row][ww];
            const float inv = 1.f / s;
#pragma unroll
            for (int n = 0; n < 4; ++n)
                P[(row0 + row) * 512 + w * 64 + n * 16 + fr] =
                    __float2bfloat16(acc[m][n][j] * inv);
        }
}

extern "C" void kernel_launch(void* const* d_in, const int* in_sizes, int n_in,
                              void* d_out, int out_size, void* d_ws, size_t ws_size,
                              hipStream_t stream) {
    const float* X = (const float*)d_in[0];
    const int* sen = (const int*)d_in[1];
    const float* W = (const float*)d_in[2];
    const float* bias = (const float*)d_in[3];
    const float* U = (const float*)d_in[4];
    float* out = (float*)d_out;

    const int B = 64, T = 512, H = 1024, A = 256;
    const long M = (long)B * T;  // 32768

    // workspace: P (32Mi) | Wt (0.5Mi) | Ut (0.25Mi)
    char* ws = (char*)d_ws;
    __hip_bfloat16* Pbf = (__hip_bfloat16*)ws;
    __hip_bfloat16* Wt = (__hip_bfloat16*)(ws + M * T * 2);
    __hip_bfloat16* Ut = (__hip_bfloat16*)((char*)Wt + (long)H * A * 2);

    // d_out scratch: alpha bf16 at [64Mi,80Mi) — consumed by score_softmax
    // before gemm_pv overwrites all of d_out with Z.
    __hip_bfloat16* alpha = (__hip_bfloat16*)((char*)d_out + M * H * 2);

    // 1. W^T [A][H], U^T [T][A]
    transpose_cvt_kernel<<<(H * A) / 256, 256, 0, stream>>>(W, Wt, H, A);
    transpose_cvt_kernel<<<(A * T) / 256, 256, 0, stream>>>(U, Ut, A, T);
    // 2. alpha = tanh(X*W + b) — r16 + T5 setprio
    gemm_xw_kernel<<<dim3(2, 256), 512, 0, stream>>>(X, Wt, alpha, bias);
    // 3. P = softmax(alpha * U^T, mask) — barrier-free K-loop
    score_softmax_kernel<<<(int)(M / 64), 512, 0, stream>>>(alpha, Ut, Pbf, sen);
    // 4. Z = P * X — r16 group-swizzle structure + T5 setprio
    gemm_pv_kernel<<<dim3(H / 128, T / 256, B), 512, 0, stream>>>(Pbf, X, out);
}